// Round 1
// baseline (1084.432 us; speedup 1.0000x reference)
//
#include <hip/hip_runtime.h>
#include <hip/hip_bf16.h>
#include <stdint.h>

// ---------------------------------------------------------------------------
// GraphConv (planetoid-gcn-residual):
//   h   = x @ W.T + bias
//   deg = histogram(rows); norm = rsqrt(1+deg)
//   h   = norm * h
//   agg[i] = sum_{e: rows[e]==i} h[cols[e]]
//   out = norm * (agg + h)
// Pipeline: deg histogram -> exclusive scan (CSR offsets) -> scatter cols ->
//           GEMM+scale -> per-row wave aggregation (atomic-free).
// ---------------------------------------------------------------------------

#define THREADS 256

// ---------------- degree histogram ----------------
__global__ void deg_kernel(const int* __restrict__ rows, int* __restrict__ deg, int E) {
    int e = blockIdx.x * THREADS + threadIdx.x;
    if (e < E) atomicAdd(&deg[rows[e]], 1);
}

// ---------------- 3-kernel exclusive scan over deg[0..n) ----------------
// scanA: each block scans 1024 elements (4/thread), writes local-exclusive
// prefix into rs, block total into bsums.
__global__ void scanA(const int* __restrict__ deg, int* __restrict__ rs,
                      int* __restrict__ bsums, int n) {
    __shared__ int s[THREADS];
    int tid  = threadIdx.x;
    int base = blockIdx.x * 1024 + tid * 4;
    int v0 = (base + 0 < n) ? deg[base + 0] : 0;
    int v1 = (base + 1 < n) ? deg[base + 1] : 0;
    int v2 = (base + 2 < n) ? deg[base + 2] : 0;
    int v3 = (base + 3 < n) ? deg[base + 3] : 0;
    int sum = v0 + v1 + v2 + v3;
    s[tid] = sum;
    __syncthreads();
    for (int off = 1; off < THREADS; off <<= 1) {
        int t = (tid >= off) ? s[tid - off] : 0;
        __syncthreads();
        s[tid] += t;
        __syncthreads();
    }
    int run = s[tid] - sum;  // exclusive prefix of this thread's chunk
    if (base + 0 < n) rs[base + 0] = run;  run += v0;
    if (base + 1 < n) rs[base + 1] = run;  run += v1;
    if (base + 2 < n) rs[base + 2] = run;  run += v2;
    if (base + 3 < n) rs[base + 3] = run;
    if (tid == THREADS - 1) bsums[blockIdx.x] = s[THREADS - 1];
}

// scanB: single block, exclusive scan of bsums[0..nb) (nb <= 256).
__global__ void scanB(int* __restrict__ bsums, int nb) {
    __shared__ int s[THREADS];
    int tid = threadIdx.x;
    int v = (tid < nb) ? bsums[tid] : 0;
    s[tid] = v;
    __syncthreads();
    for (int off = 1; off < THREADS; off <<= 1) {
        int t = (tid >= off) ? s[tid - off] : 0;
        __syncthreads();
        s[tid] += t;
        __syncthreads();
    }
    if (tid < nb) bsums[tid] = s[tid] - v;
}

// scanC: add block offsets; set rs[n] = E.
__global__ void scanC(int* __restrict__ rs, const int* __restrict__ bsums, int n, int E) {
    int tid  = threadIdx.x;
    int base = blockIdx.x * 1024 + tid * 4;
    int add  = bsums[blockIdx.x];
    if (base + 0 < n) rs[base + 0] += add;
    if (base + 1 < n) rs[base + 1] += add;
    if (base + 2 < n) rs[base + 2] += add;
    if (base + 3 < n) rs[base + 3] += add;
    if (blockIdx.x == 0 && tid == 0) rs[n] = E;
}

// ---------------- scatter edges into CSR order ----------------
__global__ void scatter_kernel(const int* __restrict__ rows, const int* __restrict__ cols,
                               const int* __restrict__ rs, int* __restrict__ cursor,
                               int* __restrict__ csr_col, int E) {
    int e = blockIdx.x * THREADS + threadIdx.x;
    if (e < E) {
        int r   = rows[e];
        int pos = rs[r] + atomicAdd(&cursor[r], 1);
        csr_col[pos] = cols[e];
    }
}

// ---------------- W transpose (Wt[k][j] = W[j][k]) ----------------
__global__ void transpose_w(const float* __restrict__ W, float* __restrict__ Wt) {
    // grid 256 (j), block 256 (k); reads coalesced, writes strided (tiny: 256KB)
    Wt[(size_t)threadIdx.x * 256 + blockIdx.x] = W[(size_t)blockIdx.x * 256 + threadIdx.x];
}

// ---------------- GEMM + bias + norm scale ----------------
// h[i][j] = rsqrt(1+deg[i]) * (sum_k x[i][k]*Wt[k][j] + bias[j])
// Block: 256 threads, 32 rows x 256 cols. Thread: 8 rows x 4 cols micro-tile.
__global__ __launch_bounds__(THREADS) void gemm_scale(
    const float* __restrict__ x, const float* __restrict__ Wt,
    const float* __restrict__ bias, const int* __restrict__ deg,
    float* __restrict__ h, int n) {
    __shared__ float xs[32 * 256];  // 32 KB
    int tid  = threadIdx.x;
    int row0 = blockIdx.x * 32;

    // stage x tile: 8192 floats = 2048 float4, 8 per thread, coalesced
    const float4* xg  = (const float4*)(x + (size_t)row0 * 256);
    float4*       xs4 = (float4*)xs;
#pragma unroll
    for (int i = 0; i < 8; i++) xs4[i * 512 + tid * 2]     = xg[i * 512 + tid * 2];
#pragma unroll
    for (int i = 0; i < 8; i++) xs4[i * 512 + tid * 2 + 1] = xg[i * 512 + tid * 2 + 1];
    __syncthreads();

    int c4 = (tid & 63) * 4;   // 4 output cols
    int r0 = (tid >> 6) * 8;   // 8 rows within tile

    float4 acc[8];
#pragma unroll
    for (int r = 0; r < 8; r++) { acc[r].x = 0.f; acc[r].y = 0.f; acc[r].z = 0.f; acc[r].w = 0.f; }

    for (int k = 0; k < 256; k += 4) {
        float4 w0 = *(const float4*)(Wt + (size_t)(k + 0) * 256 + c4);
        float4 w1 = *(const float4*)(Wt + (size_t)(k + 1) * 256 + c4);
        float4 w2 = *(const float4*)(Wt + (size_t)(k + 2) * 256 + c4);
        float4 w3 = *(const float4*)(Wt + (size_t)(k + 3) * 256 + c4);
#pragma unroll
        for (int r = 0; r < 8; r++) {
            float4 xv = *(const float4*)(xs + (r0 + r) * 256 + k);  // LDS broadcast b128
            acc[r].x += xv.x * w0.x + xv.y * w1.x + xv.z * w2.x + xv.w * w3.x;
            acc[r].y += xv.x * w0.y + xv.y * w1.y + xv.z * w2.y + xv.w * w3.y;
            acc[r].z += xv.x * w0.z + xv.y * w1.z + xv.z * w2.z + xv.w * w3.z;
            acc[r].w += xv.x * w0.w + xv.y * w1.w + xv.z * w2.w + xv.w * w3.w;
        }
    }

    float4 bb = *(const float4*)(bias + c4);
#pragma unroll
    for (int r = 0; r < 8; r++) {
        int row = row0 + r0 + r;
        float nrm = rsqrtf(1.0f + (float)deg[row]);
        float4 o;
        o.x = (acc[r].x + bb.x) * nrm;
        o.y = (acc[r].y + bb.y) * nrm;
        o.z = (acc[r].z + bb.z) * nrm;
        o.w = (acc[r].w + bb.w) * nrm;
        *(float4*)(h + (size_t)row * 256 + c4) = o;
    }
}

// ---------------- aggregation: one wave per row, atomic-free ----------------
__global__ __launch_bounds__(THREADS) void agg_kernel(
    const float* __restrict__ h, const int* __restrict__ csr_col,
    const int* __restrict__ rs, const int* __restrict__ deg,
    float* __restrict__ out, int n) {
    int row  = blockIdx.x * 4 + (threadIdx.x >> 6);
    if (row >= n) return;
    int lane = threadIdx.x & 63;
    int off  = lane * 4;

    int s   = rs[row];
    int end = rs[row + 1];

    // residual: acc starts at h_scaled[row]
    float4 acc = *(const float4*)(h + (size_t)row * 256 + off);

    int e = s;
    for (; e + 2 <= end; e += 2) {
        int c0 = csr_col[e];
        int c1 = csr_col[e + 1];
        float4 a = *(const float4*)(h + (size_t)c0 * 256 + off);
        float4 b = *(const float4*)(h + (size_t)c1 * 256 + off);
        acc.x += a.x + b.x;
        acc.y += a.y + b.y;
        acc.z += a.z + b.z;
        acc.w += a.w + b.w;
    }
    if (e < end) {
        int c = csr_col[e];
        float4 a = *(const float4*)(h + (size_t)c * 256 + off);
        acc.x += a.x; acc.y += a.y; acc.z += a.z; acc.w += a.w;
    }

    float nrm = rsqrtf(1.0f + (float)deg[row]);
    float4 o;
    o.x = acc.x * nrm; o.y = acc.y * nrm; o.z = acc.z * nrm; o.w = acc.w * nrm;
    *(float4*)(out + (size_t)row * 256 + off) = o;
}

// ---------------------------------------------------------------------------
extern "C" void kernel_launch(void* const* d_in, const int* in_sizes, int n_in,
                              void* d_out, int out_size, void* d_ws, size_t ws_size,
                              hipStream_t stream) {
    const float* x    = (const float*)d_in[0];
    const float* W    = (const float*)d_in[1];
    const float* bias = (const float*)d_in[2];
    const int*   rows = (const int*)d_in[3];
    const int*   cols = (const int*)d_in[4];

    const int D = 256;
    int n = in_sizes[0] / D;    // 100000
    int E = in_sizes[3];        // 3200000

    // ---- workspace carve (256B-aligned regions) ----
    char* p = (char*)d_ws;
    auto alignup = [](size_t v) { return (v + 255) & ~(size_t)255; };
    float* h      = (float*)p;  p += alignup((size_t)n * D * sizeof(float));   // 102.4 MB
    int*   deg    = (int*)p;    p += alignup((size_t)n * sizeof(int));
    int*   rs     = (int*)p;    p += alignup((size_t)(n + 1) * sizeof(int));
    int*   cursor = (int*)p;    p += alignup((size_t)n * sizeof(int));
    int*   bsums  = (int*)p;    p += alignup((size_t)1024);
    int*   csr    = (int*)p;    p += alignup((size_t)E * sizeof(int));         // 12.8 MB
    float* Wt     = (float*)p;  p += alignup((size_t)D * D * sizeof(float));   // 256 KB

    hipMemsetAsync(deg,    0, (size_t)n * sizeof(int), stream);
    hipMemsetAsync(cursor, 0, (size_t)n * sizeof(int), stream);

    int eblocks = (E + THREADS - 1) / THREADS;
    deg_kernel<<<eblocks, THREADS, 0, stream>>>(rows, deg, E);

    int nb = (n + 1023) / 1024;  // 98 for n=100000 (<= 256 required by scanB)
    scanA<<<nb, THREADS, 0, stream>>>(deg, rs, bsums, n);
    scanB<<<1, THREADS, 0, stream>>>(bsums, nb);
    scanC<<<nb, THREADS, 0, stream>>>(rs, bsums, n, E);

    scatter_kernel<<<eblocks, THREADS, 0, stream>>>(rows, cols, rs, cursor, csr, E);

    transpose_w<<<256, 256, 0, stream>>>(W, Wt);

    int gblocks = (n + 31) / 32;  // n divisible by 32 here
    gemm_scale<<<gblocks, THREADS, 0, stream>>>(x, Wt, bias, deg, h, n);

    int ablocks = (n + 3) / 4;
    agg_kernel<<<ablocks, THREADS, 0, stream>>>(h, csr, rs, deg, (float*)d_out, n);
}

// Round 2
// 857.602 us; speedup vs baseline: 1.2645x; 1.2645x over previous
//
#include <hip/hip_runtime.h>
#include <hip/hip_bf16.h>
#include <hip/hip_fp16.h>
#include <stdint.h>

// ---------------------------------------------------------------------------
// GraphConv (planetoid-gcn-residual):
//   h   = x @ W.T + bias
//   deg = histogram(rows); norm = rsqrt(1+deg)
//   h   = norm * h
//   agg[i] = sum_{e: rows[e]==i} h[cols[e]]
//   out = norm * (agg + h)
// Pipeline: deg histogram -> exclusive scan (CSR offsets) -> scatter cols ->
//           GEMM+scale (h stored FP16) -> per-row wave aggregation.
// R1 change: h stored as fp16 -> halves the 3.28 GB gather traffic of the
// bandwidth-bound agg kernel. fp32 accumulate; error += ~1e-4 (negligible).
// ---------------------------------------------------------------------------

#define THREADS 256

// ---------------- degree histogram ----------------
__global__ void deg_kernel(const int* __restrict__ rows, int* __restrict__ deg, int E) {
    int e = blockIdx.x * THREADS + threadIdx.x;
    if (e < E) atomicAdd(&deg[rows[e]], 1);
}

// ---------------- 3-kernel exclusive scan over deg[0..n) ----------------
__global__ void scanA(const int* __restrict__ deg, int* __restrict__ rs,
                      int* __restrict__ bsums, int n) {
    __shared__ int s[THREADS];
    int tid  = threadIdx.x;
    int base = blockIdx.x * 1024 + tid * 4;
    int v0 = (base + 0 < n) ? deg[base + 0] : 0;
    int v1 = (base + 1 < n) ? deg[base + 1] : 0;
    int v2 = (base + 2 < n) ? deg[base + 2] : 0;
    int v3 = (base + 3 < n) ? deg[base + 3] : 0;
    int sum = v0 + v1 + v2 + v3;
    s[tid] = sum;
    __syncthreads();
    for (int off = 1; off < THREADS; off <<= 1) {
        int t = (tid >= off) ? s[tid - off] : 0;
        __syncthreads();
        s[tid] += t;
        __syncthreads();
    }
    int run = s[tid] - sum;
    if (base + 0 < n) rs[base + 0] = run;  run += v0;
    if (base + 1 < n) rs[base + 1] = run;  run += v1;
    if (base + 2 < n) rs[base + 2] = run;  run += v2;
    if (base + 3 < n) rs[base + 3] = run;
    if (tid == THREADS - 1) bsums[blockIdx.x] = s[THREADS - 1];
}

__global__ void scanB(int* __restrict__ bsums, int nb) {
    __shared__ int s[THREADS];
    int tid = threadIdx.x;
    int v = (tid < nb) ? bsums[tid] : 0;
    s[tid] = v;
    __syncthreads();
    for (int off = 1; off < THREADS; off <<= 1) {
        int t = (tid >= off) ? s[tid - off] : 0;
        __syncthreads();
        s[tid] += t;
        __syncthreads();
    }
    if (tid < nb) bsums[tid] = s[tid] - v;
}

__global__ void scanC(int* __restrict__ rs, const int* __restrict__ bsums, int n, int E) {
    int tid  = threadIdx.x;
    int base = blockIdx.x * 1024 + tid * 4;
    int add  = bsums[blockIdx.x];
    if (base + 0 < n) rs[base + 0] += add;
    if (base + 1 < n) rs[base + 1] += add;
    if (base + 2 < n) rs[base + 2] += add;
    if (base + 3 < n) rs[base + 3] += add;
    if (blockIdx.x == 0 && tid == 0) rs[n] = E;
}

// ---------------- scatter edges into CSR order ----------------
__global__ void scatter_kernel(const int* __restrict__ rows, const int* __restrict__ cols,
                               const int* __restrict__ rs, int* __restrict__ cursor,
                               int* __restrict__ csr_col, int E) {
    int e = blockIdx.x * THREADS + threadIdx.x;
    if (e < E) {
        int r   = rows[e];
        int pos = rs[r] + atomicAdd(&cursor[r], 1);
        csr_col[pos] = cols[e];
    }
}

// ---------------- W transpose (Wt[k][j] = W[j][k]) ----------------
__global__ void transpose_w(const float* __restrict__ W, float* __restrict__ Wt) {
    Wt[(size_t)threadIdx.x * 256 + blockIdx.x] = W[(size_t)blockIdx.x * 256 + threadIdx.x];
}

// ---------------- GEMM + bias + norm scale, store FP16 ----------------
// h16[i][j] = (fp16) rsqrt(1+deg[i]) * (sum_k x[i][k]*Wt[k][j] + bias[j])
__global__ __launch_bounds__(THREADS) void gemm_scale(
    const float* __restrict__ x, const float* __restrict__ Wt,
    const float* __restrict__ bias, const int* __restrict__ deg,
    __half* __restrict__ h16, int n) {
    __shared__ float xs[32 * 256];  // 32 KB
    int tid  = threadIdx.x;
    int row0 = blockIdx.x * 32;

    const float4* xg  = (const float4*)(x + (size_t)row0 * 256);
    float4*       xs4 = (float4*)xs;
#pragma unroll
    for (int i = 0; i < 8; i++) xs4[i * 512 + tid * 2]     = xg[i * 512 + tid * 2];
#pragma unroll
    for (int i = 0; i < 8; i++) xs4[i * 512 + tid * 2 + 1] = xg[i * 512 + tid * 2 + 1];
    __syncthreads();

    int c4 = (tid & 63) * 4;   // 4 output cols
    int r0 = (tid >> 6) * 8;   // 8 rows within tile

    float4 acc[8];
#pragma unroll
    for (int r = 0; r < 8; r++) { acc[r].x = 0.f; acc[r].y = 0.f; acc[r].z = 0.f; acc[r].w = 0.f; }

    for (int k = 0; k < 256; k += 4) {
        float4 w0 = *(const float4*)(Wt + (size_t)(k + 0) * 256 + c4);
        float4 w1 = *(const float4*)(Wt + (size_t)(k + 1) * 256 + c4);
        float4 w2 = *(const float4*)(Wt + (size_t)(k + 2) * 256 + c4);
        float4 w3 = *(const float4*)(Wt + (size_t)(k + 3) * 256 + c4);
#pragma unroll
        for (int r = 0; r < 8; r++) {
            float4 xv = *(const float4*)(xs + (r0 + r) * 256 + k);
            acc[r].x += xv.x * w0.x + xv.y * w1.x + xv.z * w2.x + xv.w * w3.x;
            acc[r].y += xv.x * w0.y + xv.y * w1.y + xv.z * w2.y + xv.w * w3.y;
            acc[r].z += xv.x * w0.z + xv.y * w1.z + xv.z * w2.z + xv.w * w3.z;
            acc[r].w += xv.x * w0.w + xv.y * w1.w + xv.z * w2.w + xv.w * w3.w;
        }
    }

    float4 bb = *(const float4*)(bias + c4);
#pragma unroll
    for (int r = 0; r < 8; r++) {
        int row = row0 + r0 + r;
        float nrm = rsqrtf(1.0f + (float)deg[row]);
        __half2 p0 = __floats2half2_rn((acc[r].x + bb.x) * nrm, (acc[r].y + bb.y) * nrm);
        __half2 p1 = __floats2half2_rn((acc[r].z + bb.z) * nrm, (acc[r].w + bb.w) * nrm);
        uint2 pk;
        pk.x = *(unsigned int*)&p0;
        pk.y = *(unsigned int*)&p1;
        *(uint2*)(h16 + (size_t)row * 256 + c4) = pk;  // 8B store
    }
}

// ---------------- aggregation: one wave per row, fp16 gather ----------------
__global__ __launch_bounds__(THREADS) void agg_kernel(
    const __half* __restrict__ h16, const int* __restrict__ csr_col,
    const int* __restrict__ rs, const int* __restrict__ deg,
    float* __restrict__ out, int n) {
    int row  = blockIdx.x * 4 + (threadIdx.x >> 6);
    if (row >= n) return;
    int lane = threadIdx.x & 63;
    int off  = lane * 4;   // 4 fp16 columns per lane

    int s   = rs[row];
    int end = rs[row + 1];

    float4 acc;
    {   // residual: h_scaled[row]
        uint2 u = *(const uint2*)(h16 + (size_t)row * 256 + off);
        __half2 p0 = *(__half2*)&u.x;
        __half2 p1 = *(__half2*)&u.y;
        acc.x = __low2float(p0); acc.y = __high2float(p0);
        acc.z = __low2float(p1); acc.w = __high2float(p1);
    }

    int e = s;
    // unroll by 4 edges to keep multiple 8B gathers in flight
    for (; e + 4 <= end; e += 4) {
        int c0 = csr_col[e];
        int c1 = csr_col[e + 1];
        int c2 = csr_col[e + 2];
        int c3 = csr_col[e + 3];
        uint2 u0 = *(const uint2*)(h16 + (size_t)c0 * 256 + off);
        uint2 u1 = *(const uint2*)(h16 + (size_t)c1 * 256 + off);
        uint2 u2 = *(const uint2*)(h16 + (size_t)c2 * 256 + off);
        uint2 u3 = *(const uint2*)(h16 + (size_t)c3 * 256 + off);
        __half2 a0 = *(__half2*)&u0.x, b0 = *(__half2*)&u0.y;
        __half2 a1 = *(__half2*)&u1.x, b1 = *(__half2*)&u1.y;
        __half2 a2 = *(__half2*)&u2.x, b2 = *(__half2*)&u2.y;
        __half2 a3 = *(__half2*)&u3.x, b3 = *(__half2*)&u3.y;
        acc.x += __low2float(a0) + __low2float(a1) + __low2float(a2) + __low2float(a3);
        acc.y += __high2float(a0) + __high2float(a1) + __high2float(a2) + __high2float(a3);
        acc.z += __low2float(b0) + __low2float(b1) + __low2float(b2) + __low2float(b3);
        acc.w += __high2float(b0) + __high2float(b1) + __high2float(b2) + __high2float(b3);
    }
    for (; e < end; e++) {
        int c = csr_col[e];
        uint2 u = *(const uint2*)(h16 + (size_t)c * 256 + off);
        __half2 p0 = *(__half2*)&u.x;
        __half2 p1 = *(__half2*)&u.y;
        acc.x += __low2float(p0); acc.y += __high2float(p0);
        acc.z += __low2float(p1); acc.w += __high2float(p1);
    }

    float nrm = rsqrtf(1.0f + (float)deg[row]);
    float4 o;
    o.x = acc.x * nrm; o.y = acc.y * nrm; o.z = acc.z * nrm; o.w = acc.w * nrm;
    *(float4*)(out + (size_t)row * 256 + off) = o;
}

// ---------------------------------------------------------------------------
extern "C" void kernel_launch(void* const* d_in, const int* in_sizes, int n_in,
                              void* d_out, int out_size, void* d_ws, size_t ws_size,
                              hipStream_t stream) {
    const float* x    = (const float*)d_in[0];
    const float* W    = (const float*)d_in[1];
    const float* bias = (const float*)d_in[2];
    const int*   rows = (const int*)d_in[3];
    const int*   cols = (const int*)d_in[4];

    const int D = 256;
    int n = in_sizes[0] / D;    // 100000
    int E = in_sizes[3];        // 3200000

    // ---- workspace carve (256B-aligned regions) ----
    char* p = (char*)d_ws;
    auto alignup = [](size_t v) { return (v + 255) & ~(size_t)255; };
    __half* h16   = (__half*)p; p += alignup((size_t)n * D * sizeof(__half));  // 51.2 MB
    int*   deg    = (int*)p;    p += alignup((size_t)n * sizeof(int));
    int*   rs     = (int*)p;    p += alignup((size_t)(n + 1) * sizeof(int));
    int*   cursor = (int*)p;    p += alignup((size_t)n * sizeof(int));
    int*   bsums  = (int*)p;    p += alignup((size_t)1024);
    int*   csr    = (int*)p;    p += alignup((size_t)E * sizeof(int));         // 12.8 MB
    float* Wt     = (float*)p;  p += alignup((size_t)D * D * sizeof(float));   // 256 KB

    hipMemsetAsync(deg,    0, (size_t)n * sizeof(int), stream);
    hipMemsetAsync(cursor, 0, (size_t)n * sizeof(int), stream);

    int eblocks = (E + THREADS - 1) / THREADS;
    deg_kernel<<<eblocks, THREADS, 0, stream>>>(rows, deg, E);

    int nb = (n + 1023) / 1024;  // 98 blocks for n=100000
    scanA<<<nb, THREADS, 0, stream>>>(deg, rs, bsums, n);
    scanB<<<1, THREADS, 0, stream>>>(bsums, nb);
    scanC<<<nb, THREADS, 0, stream>>>(rs, bsums, n, E);

    scatter_kernel<<<eblocks, THREADS, 0, stream>>>(rows, cols, rs, cursor, csr, E);

    transpose_w<<<256, 256, 0, stream>>>(W, Wt);

    int gblocks = (n + 31) / 32;
    gemm_scale<<<gblocks, THREADS, 0, stream>>>(x, Wt, bias, deg, h16, n);

    int ablocks = (n + 3) / 4;
    agg_kernel<<<ablocks, THREADS, 0, stream>>>(h16, csr, rs, deg, (float*)d_out, n);
}

// Round 3
// 743.556 us; speedup vs baseline: 1.4584x; 1.1534x over previous
//
#include <hip/hip_runtime.h>
#include <hip/hip_fp16.h>
#include <stdint.h>

// ---------------------------------------------------------------------------
// GraphConv (planetoid-gcn-residual):
//   h   = norm * (x @ W.T + bias),  norm = rsqrt(1+deg)
//   out = norm * (spmm_add(adj,h) + h)
// Pipeline: deg histogram -> scan (CSR) -> scatter -> f16-MFMA GEMM+scale ->
//           per-row wave aggregation (half-wave per edge, dwordx4 gathers).
// R2: GEMM moved to mfma_f32_16x16x32_f16 (no fp32 MFMA on CDNA4); W
//     pre-swizzled to B-frag layout; x staged fp32->f16 in LDS A-frag layout.
//     agg: 32 lanes x 16B per edge, 2 edges per wave-instr, cross-half shfl.
// ---------------------------------------------------------------------------

#define THREADS 256

typedef _Float16 half8 __attribute__((ext_vector_type(8)));
typedef float floatx4 __attribute__((ext_vector_type(4)));

// ---------------- degree histogram ----------------
__global__ void deg_kernel(const int* __restrict__ rows, int* __restrict__ deg, int E) {
    int e = blockIdx.x * THREADS + threadIdx.x;
    if (e < E) atomicAdd(&deg[rows[e]], 1);
}

// ---------------- 3-kernel exclusive scan over deg[0..n) ----------------
__global__ void scanA(const int* __restrict__ deg, int* __restrict__ rs,
                      int* __restrict__ bsums, int n) {
    __shared__ int s[THREADS];
    int tid  = threadIdx.x;
    int base = blockIdx.x * 1024 + tid * 4;
    int v0 = (base + 0 < n) ? deg[base + 0] : 0;
    int v1 = (base + 1 < n) ? deg[base + 1] : 0;
    int v2 = (base + 2 < n) ? deg[base + 2] : 0;
    int v3 = (base + 3 < n) ? deg[base + 3] : 0;
    int sum = v0 + v1 + v2 + v3;
    s[tid] = sum;
    __syncthreads();
    for (int off = 1; off < THREADS; off <<= 1) {
        int t = (tid >= off) ? s[tid - off] : 0;
        __syncthreads();
        s[tid] += t;
        __syncthreads();
    }
    int run = s[tid] - sum;
    if (base + 0 < n) rs[base + 0] = run;  run += v0;
    if (base + 1 < n) rs[base + 1] = run;  run += v1;
    if (base + 2 < n) rs[base + 2] = run;  run += v2;
    if (base + 3 < n) rs[base + 3] = run;
    if (tid == THREADS - 1) bsums[blockIdx.x] = s[THREADS - 1];
}

__global__ void scanB(int* __restrict__ bsums, int nb) {
    __shared__ int s[THREADS];
    int tid = threadIdx.x;
    int v = (tid < nb) ? bsums[tid] : 0;
    s[tid] = v;
    __syncthreads();
    for (int off = 1; off < THREADS; off <<= 1) {
        int t = (tid >= off) ? s[tid - off] : 0;
        __syncthreads();
        s[tid] += t;
        __syncthreads();
    }
    if (tid < nb) bsums[tid] = s[tid] - v;
}

__global__ void scanC(int* __restrict__ rs, const int* __restrict__ bsums, int n, int E) {
    int tid  = threadIdx.x;
    int base = blockIdx.x * 1024 + tid * 4;
    int add  = bsums[blockIdx.x];
    if (base + 0 < n) rs[base + 0] += add;
    if (base + 1 < n) rs[base + 1] += add;
    if (base + 2 < n) rs[base + 2] += add;
    if (base + 3 < n) rs[base + 3] += add;
    if (blockIdx.x == 0 && tid == 0) rs[n] = E;
}

// ---------------- scatter edges into CSR order ----------------
__global__ void scatter_kernel(const int* __restrict__ rows, const int* __restrict__ cols,
                               const int* __restrict__ rs, int* __restrict__ cursor,
                               int* __restrict__ csr_col, int E) {
    int e = blockIdx.x * THREADS + threadIdx.x;
    if (e < E) {
        int r   = rows[e];
        int pos = rs[r] + atomicAdd(&cursor[r], 1);
        csr_col[pos] = cols[e];
    }
}

// ---------------- W -> f16 B-fragment swizzle ----------------
// Bswz[((n_tile*8 + k_step)*64 + lane)] = 8 f16: B[k][n] = W[n][k] with
// n = n_tile*16 + (lane&15), k = k_step*32 + (lane>>4)*8 + j (j=0..7).
__global__ void make_bswz(const float* __restrict__ W, half8* __restrict__ Bswz) {
    int t = blockIdx.x * THREADS + threadIdx.x;   // 8192 entries
    int n_tile = t >> 9;
    int k_step = (t >> 6) & 7;
    int lane   = t & 63;
    int q = lane >> 4, m16 = lane & 15;
    const float* src = W + (size_t)(n_tile * 16 + m16) * 256 + k_step * 32 + q * 8;
    half8 h;
#pragma unroll
    for (int j = 0; j < 8; j++) h[j] = (_Float16)src[j];
    Bswz[t] = h;
}

// ---------------- f16 MFMA GEMM + bias + norm scale ----------------
// Block: 256 thr = 4 waves. Tile: 64 rows x 256 cols; wave w -> cols [64w,64w+64).
// Wave: 4x4 grid of 16x16x32 accumulators. A staged in LDS A-frag layout.
__global__ __launch_bounds__(THREADS) void gemm_mfma(
    const float* __restrict__ x, const half8* __restrict__ Bswz,
    const float* __restrict__ bias, const int* __restrict__ deg,
    _Float16* __restrict__ h16, int n) {
    __shared__ _Float16 As[4 * 8 * 64 * 8];   // 32 KB, A-frag layout
    int tid  = threadIdx.x;
    int row0 = blockIdx.x * 64;

    // stage x tile fp32 -> f16 into A-frag layout
#pragma unroll
    for (int i = 0; i < 16; i++) {
        int flat = i * THREADS + tid;
        int r  = flat >> 6;         // 0..63 row in tile
        int k  = (flat & 63) * 4;   // 0..252 step 4
        float4 v;
        if (row0 + r < n) v = *(const float4*)(x + (size_t)(row0 + r) * 256 + k);
        else { v.x = 0.f; v.y = 0.f; v.z = 0.f; v.w = 0.f; }
        int m_sub  = r >> 4;
        int k_step = k >> 5;
        int q      = (k >> 3) & 3;
        int j      = k & 7;         // 0 or 4
        int lane_w = (r & 15) + (q << 4);
        int entry  = (m_sub * 8 + k_step) * 64 + lane_w;
        union { _Float16 h[4]; uint2 u; } pk;
        pk.h[0] = (_Float16)v.x; pk.h[1] = (_Float16)v.y;
        pk.h[2] = (_Float16)v.z; pk.h[3] = (_Float16)v.w;
        *(uint2*)(As + entry * 8 + j) = pk.u;
    }
    __syncthreads();

    int w    = tid >> 6;    // wave id = n-slice
    int lane = tid & 63;

    floatx4 acc[4][4];
#pragma unroll
    for (int ms = 0; ms < 4; ms++)
#pragma unroll
        for (int nn = 0; nn < 4; nn++) {
            acc[ms][nn][0] = 0.f; acc[ms][nn][1] = 0.f;
            acc[ms][nn][2] = 0.f; acc[ms][nn][3] = 0.f;
        }

    for (int ks = 0; ks < 8; ks++) {
        half8 bfrag[4];
#pragma unroll
        for (int nn = 0; nn < 4; nn++)
            bfrag[nn] = Bswz[((w * 4 + nn) * 8 + ks) * 64 + lane];
        half8 afrag[4];
#pragma unroll
        for (int ms = 0; ms < 4; ms++)
            afrag[ms] = *(const half8*)(As + ((ms * 8 + ks) * 64 + lane) * 8);
#pragma unroll
        for (int ms = 0; ms < 4; ms++)
#pragma unroll
            for (int nn = 0; nn < 4; nn++)
                acc[ms][nn] = __builtin_amdgcn_mfma_f32_16x16x32_f16(
                    afrag[ms], bfrag[nn], acc[ms][nn], 0, 0, 0);
    }

    // epilogue: C/D layout col=lane&15, row=(lane>>4)*4+i
    int rgrp = lane >> 4;
    int cl   = lane & 15;
#pragma unroll
    for (int ms = 0; ms < 4; ms++) {
        int rbase = row0 + ms * 16 + rgrp * 4;
        float nrm[4];
#pragma unroll
        for (int i = 0; i < 4; i++) {
            int r = rbase + i;
            nrm[i] = (r < n) ? rsqrtf(1.0f + (float)deg[r]) : 0.f;
        }
#pragma unroll
        for (int nn = 0; nn < 4; nn++) {
            int col = w * 64 + nn * 16 + cl;
            float bb = bias[col];
#pragma unroll
            for (int i = 0; i < 4; i++) {
                int r = rbase + i;
                if (r < n)
                    h16[(size_t)r * 256 + col] =
                        (_Float16)((acc[ms][nn][i] + bb) * nrm[i]);
            }
        }
    }
}

// ---------------- aggregation: wave per row, half-wave per edge ----------------
__global__ __launch_bounds__(THREADS) void agg_kernel(
    const _Float16* __restrict__ h16, const int* __restrict__ csr_col,
    const int* __restrict__ rs, const int* __restrict__ deg,
    float* __restrict__ out, int n) {
    int row = blockIdx.x * 4 + (threadIdx.x >> 6);
    if (row >= n) return;
    int lane = threadIdx.x & 63;
    int half = lane >> 5;
    int l32  = lane & 31;
    int off  = l32 * 8;   // 8 f16 cols per lane, 32 lanes cover the row

    int s   = rs[row];
    int end = rs[row + 1];

    float acc[8] = {0.f, 0.f, 0.f, 0.f, 0.f, 0.f, 0.f, 0.f};
    if (half == 0) {   // residual h_scaled[row]
        half8 v = *(const half8*)(h16 + (size_t)row * 256 + off);
#pragma unroll
        for (int j = 0; j < 8; j++) acc[j] = (float)v[j];
    }

    int e = s + half;   // half 0 takes even-offset edges, half 1 odd
    for (; e + 2 < end; e += 4) {
        int c0 = csr_col[e];
        int c1 = csr_col[e + 2];
        half8 v0 = *(const half8*)(h16 + (size_t)c0 * 256 + off);
        half8 v1 = *(const half8*)(h16 + (size_t)c1 * 256 + off);
#pragma unroll
        for (int j = 0; j < 8; j++) acc[j] += (float)v0[j] + (float)v1[j];
    }
    for (; e < end; e += 2) {
        int c = csr_col[e];
        half8 v = *(const half8*)(h16 + (size_t)c * 256 + off);
#pragma unroll
        for (int j = 0; j < 8; j++) acc[j] += (float)v[j];
    }

    // cross-half reduction: lane L += lane L+32
#pragma unroll
    for (int j = 0; j < 8; j++) acc[j] += __shfl_down(acc[j], 32);

    if (half == 0) {
        float nrm = rsqrtf(1.0f + (float)deg[row]);
        float4 o0, o1;
        o0.x = acc[0] * nrm; o0.y = acc[1] * nrm; o0.z = acc[2] * nrm; o0.w = acc[3] * nrm;
        o1.x = acc[4] * nrm; o1.y = acc[5] * nrm; o1.z = acc[6] * nrm; o1.w = acc[7] * nrm;
        float* dst = out + (size_t)row * 256 + off;
        *(float4*)dst       = o0;
        *(float4*)(dst + 4) = o1;
    }
}

// ---------------------------------------------------------------------------
extern "C" void kernel_launch(void* const* d_in, const int* in_sizes, int n_in,
                              void* d_out, int out_size, void* d_ws, size_t ws_size,
                              hipStream_t stream) {
    const float* x    = (const float*)d_in[0];
    const float* W    = (const float*)d_in[1];
    const float* bias = (const float*)d_in[2];
    const int*   rows = (const int*)d_in[3];
    const int*   cols = (const int*)d_in[4];

    const int D = 256;
    int n = in_sizes[0] / D;    // 100000
    int E = in_sizes[3];        // 3200000

    // ---- workspace carve ----
    char* p = (char*)d_ws;
    auto alignup = [](size_t v) { return (v + 255) & ~(size_t)255; };
    _Float16* h16 = (_Float16*)p; p += alignup((size_t)n * D * sizeof(_Float16)); // 51.2 MB
    int*   deg    = (int*)p;    p += alignup((size_t)n * sizeof(int));
    int*   rs     = (int*)p;    p += alignup((size_t)(n + 1) * sizeof(int));
    int*   cursor = (int*)p;    p += alignup((size_t)n * sizeof(int));
    int*   bsums  = (int*)p;    p += alignup((size_t)1024);
    int*   csr    = (int*)p;    p += alignup((size_t)E * sizeof(int));            // 12.8 MB
    half8* Bswz   = (half8*)p;  p += alignup((size_t)8192 * sizeof(half8));       // 128 KB

    hipMemsetAsync(deg,    0, (size_t)n * sizeof(int), stream);
    hipMemsetAsync(cursor, 0, (size_t)n * sizeof(int), stream);

    int eblocks = (E + THREADS - 1) / THREADS;
    deg_kernel<<<eblocks, THREADS, 0, stream>>>(rows, deg, E);

    int nb = (n + 1023) / 1024;  // 98 <= 256
    scanA<<<nb, THREADS, 0, stream>>>(deg, rs, bsums, n);
    scanB<<<1, THREADS, 0, stream>>>(bsums, nb);
    scanC<<<nb, THREADS, 0, stream>>>(rs, bsums, n, E);

    scatter_kernel<<<eblocks, THREADS, 0, stream>>>(rows, cols, rs, cursor, csr, E);

    make_bswz<<<32, THREADS, 0, stream>>>(W, Bswz);

    int gblocks = (n + 63) / 64;   // 1563
    gemm_mfma<<<gblocks, THREADS, 0, stream>>>(x, Bswz, bias, deg, h16, n);

    int ablocks = (n + 3) / 4;
    agg_kernel<<<ablocks, THREADS, 0, stream>>>(h16, csr, rs, deg, (float*)d_out, n);
}